// Round 1
// baseline (187.706 us; speedup 1.0000x reference)
//
#include <hip/hip_runtime.h>
#include <math.h>

#define H 2048
#define V 50257
#define ML 25

// ws layout (floats)
#define WS_M   0           // max logit
#define WS_L   1           // log-sum-exp
#define WS_EMB 16          // embedded [H]
#define WS_ATT (WS_EMB + H)  // attn_applied [H]  (contiguous after EMB -> cat vector)
#define WS_X   (WS_ATT + H)  // relu(combine) [H]

// ---------------- Kernel 1: embedding + attention + attn_applied ----------------
__global__ __launch_bounds__(1024)
void k1_attn(const int* tok_p, const float* hidden, const float* enc_outs,
             const float* emb, const float* W_attn, const float* b_attn,
             float* ws, float* out_attnw)
{
    __shared__ __align__(16) float s_cat[2 * H];
    __shared__ float s_w[ML];
    const int tid = threadIdx.x;
    const int tok = tok_p[0];   // int64 input: low word (LE, tok < 2^31)
    const float* erow = emb + (size_t)tok * H;
    for (int h = tid; h < H; h += 1024) {
        float e = erow[h];
        s_cat[h] = e;
        ws[WS_EMB + h] = e;
        s_cat[H + h] = hidden[h];
    }
    __syncthreads();

    const int wave = tid >> 6, lane = tid & 63;
    for (int l = wave; l < ML; l += 16) {
        const float* wrow = W_attn + (size_t)l * (2 * H);
        float acc = 0.f;
        for (int j = lane; j < 2 * H; j += 64)
            acc += wrow[j] * s_cat[j];
        #pragma unroll
        for (int off = 32; off; off >>= 1) acc += __shfl_xor(acc, off);
        if (lane == 0) s_w[l] = acc + b_attn[l];
    }
    __syncthreads();

    if (tid == 0) {   // softmax over 25 values — trivial scalar
        float m = s_w[0];
        for (int l = 1; l < ML; ++l) m = fmaxf(m, s_w[l]);
        float s = 0.f;
        for (int l = 0; l < ML; ++l) { float e = expf(s_w[l] - m); s_w[l] = e; s += e; }
        float inv = 1.f / s;
        for (int l = 0; l < ML; ++l) { s_w[l] *= inv; out_attnw[l] = s_w[l]; }
    }
    __syncthreads();

    for (int h = tid; h < H; h += 1024) {
        float acc = 0.f;
        #pragma unroll
        for (int l = 0; l < ML; ++l)
            acc += s_w[l] * enc_outs[(size_t)l * H + h];
        ws[WS_ATT + h] = acc;
    }
}

// ---------------- Kernel 2: combine GEMV (H x 2H) + bias + relu ----------------
__global__ __launch_bounds__(256)
void k2_combine(const float* W_comb, const float* b_comb, float* ws)
{
    __shared__ __align__(16) float s_cat[2 * H];
    const int tid = threadIdx.x;
    for (int j = tid; j < 2 * H; j += 256) s_cat[j] = ws[WS_EMB + j];
    __syncthreads();

    const int wave = tid >> 6, lane = tid & 63;
    const int k = blockIdx.x * 4 + wave;
    const float4* w4 = reinterpret_cast<const float4*>(W_comb + (size_t)k * (2 * H));
    const float4* c4 = reinterpret_cast<const float4*>(s_cat);
    float acc = 0.f;
    #pragma unroll
    for (int t = 0; t < 16; ++t) {
        float4 a = w4[t * 64 + lane];
        float4 b = c4[t * 64 + lane];
        acc += a.x * b.x + a.y * b.y + a.z * b.z + a.w * b.w;
    }
    #pragma unroll
    for (int off = 32; off; off >>= 1) acc += __shfl_xor(acc, off);
    if (lane == 0) ws[WS_X + k] = fmaxf(acc + b_comb[k], 0.f);
}

// ---------------- Kernel 3: GRU cell (6 GEMV rows per output element) ----------------
__global__ __launch_bounds__(256)
void k3_gru(const float* W_ih, const float* W_hh, const float* b_ih, const float* b_hh,
            const float* hidden, const float* ws, float* h_out)
{
    __shared__ __align__(16) float s_x[H];
    __shared__ __align__(16) float s_h[H];
    const int tid = threadIdx.x;
    for (int j = tid; j < H; j += 256) { s_x[j] = ws[WS_X + j]; s_h[j] = hidden[j]; }
    __syncthreads();

    const int wave = tid >> 6, lane = tid & 63;
    const int k = blockIdx.x * 4 + wave;
    const float4* x4 = reinterpret_cast<const float4*>(s_x);
    const float4* h4 = reinterpret_cast<const float4*>(s_h);
    const float4* wi_r = reinterpret_cast<const float4*>(W_ih + (size_t)k * H);
    const float4* wi_z = reinterpret_cast<const float4*>(W_ih + (size_t)(k + H) * H);
    const float4* wi_n = reinterpret_cast<const float4*>(W_ih + (size_t)(k + 2 * H) * H);
    const float4* wh_r = reinterpret_cast<const float4*>(W_hh + (size_t)k * H);
    const float4* wh_z = reinterpret_cast<const float4*>(W_hh + (size_t)(k + H) * H);
    const float4* wh_n = reinterpret_cast<const float4*>(W_hh + (size_t)(k + 2 * H) * H);

    float a_r = 0, a_z = 0, a_n = 0, g_r = 0, g_z = 0, g_n = 0;
    #pragma unroll
    for (int t = 0; t < 8; ++t) {
        int idx = t * 64 + lane;
        float4 xv = x4[idx], hv = h4[idx];
        float4 w;
        w = wi_r[idx]; a_r += w.x * xv.x + w.y * xv.y + w.z * xv.z + w.w * xv.w;
        w = wi_z[idx]; a_z += w.x * xv.x + w.y * xv.y + w.z * xv.z + w.w * xv.w;
        w = wi_n[idx]; a_n += w.x * xv.x + w.y * xv.y + w.z * xv.z + w.w * xv.w;
        w = wh_r[idx]; g_r += w.x * hv.x + w.y * hv.y + w.z * hv.z + w.w * hv.w;
        w = wh_z[idx]; g_z += w.x * hv.x + w.y * hv.y + w.z * hv.z + w.w * hv.w;
        w = wh_n[idx]; g_n += w.x * hv.x + w.y * hv.y + w.z * hv.z + w.w * hv.w;
    }
    #pragma unroll
    for (int off = 32; off; off >>= 1) {
        a_r += __shfl_xor(a_r, off); a_z += __shfl_xor(a_z, off); a_n += __shfl_xor(a_n, off);
        g_r += __shfl_xor(g_r, off); g_z += __shfl_xor(g_z, off); g_n += __shfl_xor(g_n, off);
    }
    if (lane == 0) {
        float ir = a_r + b_ih[k], iz = a_z + b_ih[k + H], inn = a_n + b_ih[k + 2 * H];
        float hr = g_r + b_hh[k], hz = g_z + b_hh[k + H], hn = g_n + b_hh[k + 2 * H];
        float r = 1.f / (1.f + expf(-(ir + hr)));
        float z = 1.f / (1.f + expf(-(iz + hz)));
        float n = tanhf(inn + r * hn);
        h_out[k] = (1.f - z) * n + z * s_h[k];
    }
}

// ---------------- Kernel 4: vocab projection GEMV (V x H) ----------------
__global__ __launch_bounds__(256)
void k4_logits(const float* __restrict__ W_out, const float* __restrict__ b_out,
               const float* __restrict__ h_new, float* __restrict__ logits)
{
    __shared__ __align__(16) float s_h[H];
    const int tid = threadIdx.x;
    for (int j = tid; j < H; j += 256) s_h[j] = h_new[j];
    __syncthreads();

    const int wave = tid >> 6, lane = tid & 63;
    const int row = blockIdx.x * 4 + wave;
    if (row >= V) return;
    const float4* w4 = reinterpret_cast<const float4*>(W_out + (size_t)row * H);
    const float4* h4 = reinterpret_cast<const float4*>(s_h);
    float acc = 0.f;
    #pragma unroll
    for (int t = 0; t < 8; ++t) {
        int idx = t * 64 + lane;
        float4 a = w4[idx], b = h4[idx];
        acc += a.x * b.x + a.y * b.y + a.z * b.z + a.w * b.w;
    }
    #pragma unroll
    for (int off = 32; off; off >>= 1) acc += __shfl_xor(acc, off);
    if (lane == 0) logits[row] = acc + b_out[row];
}

// ---------------- Kernel 5: single-block max + log-sum-exp over V ----------------
__global__ __launch_bounds__(1024)
void k5_reduce(const float* __restrict__ logits, float* ws)
{
    __shared__ float s_red[16];
    const int tid = threadIdx.x;
    const int wave = tid >> 6, lane = tid & 63;

    float m = -1e30f;
    for (int v = tid; v < V; v += 1024) m = fmaxf(m, logits[v]);
    #pragma unroll
    for (int off = 32; off; off >>= 1) m = fmaxf(m, __shfl_xor(m, off));
    if (lane == 0) s_red[wave] = m;
    __syncthreads();
    if (tid == 0) {
        float mm = s_red[0];
        for (int w = 1; w < 16; ++w) mm = fmaxf(mm, s_red[w]);
        s_red[0] = mm;
    }
    __syncthreads();
    m = s_red[0];
    __syncthreads();

    float s = 0.f;
    for (int v = tid; v < V; v += 1024) s += expf(logits[v] - m);
    #pragma unroll
    for (int off = 32; off; off >>= 1) s += __shfl_xor(s, off);
    if (lane == 0) s_red[wave] = s;
    __syncthreads();
    if (tid == 0) {
        float ss = 0.f;
        for (int w = 0; w < 16; ++w) ss += s_red[w];
        ws[WS_M] = m;
        ws[WS_L] = logf(ss);
    }
}

// ---------------- Kernel 6: apply log-softmax in place ----------------
__global__ __launch_bounds__(256)
void k6_apply(float* logits, const float* ws)
{
    const int v = blockIdx.x * 256 + threadIdx.x;
    if (v < V) logits[v] = logits[v] - ws[WS_M] - ws[WS_L];
}

extern "C" void kernel_launch(void* const* d_in, const int* in_sizes, int n_in,
                              void* d_out, int out_size, void* d_ws, size_t ws_size,
                              hipStream_t stream)
{
    const int*   tok      = (const int*)d_in[0];     // int64, read low word
    const float* hidden   = (const float*)d_in[1];   // [1,1,H]
    // d_in[2] = encoder_output: unused by reference
    const float* enc_outs = (const float*)d_in[3];   // [ML,H]
    const float* emb      = (const float*)d_in[4];   // [V,H]
    const float* W_attn   = (const float*)d_in[5];   // [ML,2H]
    const float* b_attn   = (const float*)d_in[6];
    const float* W_comb   = (const float*)d_in[7];   // [H,2H]
    const float* b_comb   = (const float*)d_in[8];
    const float* W_ih     = (const float*)d_in[9];   // [3H,H]
    const float* W_hh     = (const float*)d_in[10];  // [3H,H]
    const float* b_ih     = (const float*)d_in[11];
    const float* b_hh     = (const float*)d_in[12];
    const float* W_out    = (const float*)d_in[13];  // [V,H]
    const float* b_out    = (const float*)d_in[14];

    float* out    = (float*)d_out;
    float* ws     = (float*)d_ws;
    float* logits = out;            // [0, V)
    float* h_out  = out + V;        // [V, V+H)
    float* attnw  = out + V + H;    // [V+H, V+H+ML)

    k1_attn   <<<1,           1024, 0, stream>>>(tok, hidden, enc_outs, emb, W_attn, b_attn, ws, attnw);
    k2_combine<<<H / 4,        256, 0, stream>>>(W_comb, b_comb, ws);
    k3_gru    <<<H / 4,        256, 0, stream>>>(W_ih, W_hh, b_ih, b_hh, hidden, ws, h_out);
    k4_logits <<<(V + 3) / 4,  256, 0, stream>>>(W_out, b_out, h_out, logits);
    k5_reduce <<<1,           1024, 0, stream>>>(logits, ws);
    k6_apply  <<<(V + 255) / 256, 256, 0, stream>>>(logits, ws);
}

// Round 2
// 117.516 us; speedup vs baseline: 1.5973x; 1.5973x over previous
//
#include <hip/hip_runtime.h>
#include <math.h>

#define H 2048
#define V 50257
#define ML 25

#define NB4 ((V + 7) / 8)   // 6283 blocks in k4 (8 rows per block)

// ws layout (floats)
#define WS_M   0                 // max logit
#define WS_L   1                 // log-sum-exp
#define WS_EMB 16                // embedded [H]
#define WS_ATT (WS_EMB + H)      // attn_applied [H] (contiguous -> cat vector of 2H)
#define WS_X   (WS_ATT + H)      // relu(combine) [H]
#define WS_PM  (WS_X + H)        // per-block max partials [NB4]
#define WS_PS  (WS_PM + 6400)    // per-block sumexp partials [NB4]

typedef float f4v __attribute__((ext_vector_type(4)));

__device__ __forceinline__ f4v ntload(const f4v* p) {
    return __builtin_nontemporal_load(p);
}
__device__ __forceinline__ float dot4(f4v a, f4v b) {
    return a[0] * b[0] + a[1] * b[1] + a[2] * b[2] + a[3] * b[3];
}

// ---------------- Kernel 1: embedding + attention + attn_applied ----------------
__global__ __launch_bounds__(1024)
void k1_attn(const int* tok_p, const float* hidden, const float* enc_outs,
             const float* emb, const float* W_attn, const float* b_attn,
             float* ws, float* out_attnw)
{
    __shared__ __align__(16) float s_cat[2 * H];
    __shared__ float s_w[ML];
    const int tid = threadIdx.x;
    const int tok = tok_p[0];   // int64 input: low word (LE, tok < 2^31)
    const float* erow = emb + (size_t)tok * H;
    for (int h = tid; h < H; h += 1024) {
        float e = erow[h];
        s_cat[h] = e;
        ws[WS_EMB + h] = e;
        s_cat[H + h] = hidden[h];
    }
    __syncthreads();

    const int wave = tid >> 6, lane = tid & 63;
    for (int l = wave; l < ML; l += 16) {
        const float* wrow = W_attn + (size_t)l * (2 * H);
        float acc = 0.f;
        for (int j = lane; j < 2 * H; j += 64)
            acc += wrow[j] * s_cat[j];
        #pragma unroll
        for (int off = 32; off; off >>= 1) acc += __shfl_xor(acc, off);
        if (lane == 0) s_w[l] = acc + b_attn[l];
    }
    __syncthreads();

    if (tid == 0) {   // softmax over 25 values — trivial scalar
        float m = s_w[0];
        for (int l = 1; l < ML; ++l) m = fmaxf(m, s_w[l]);
        float s = 0.f;
        for (int l = 0; l < ML; ++l) { float e = expf(s_w[l] - m); s_w[l] = e; s += e; }
        float inv = 1.f / s;
        for (int l = 0; l < ML; ++l) { s_w[l] *= inv; out_attnw[l] = s_w[l]; }
    }
    __syncthreads();

    for (int h = tid; h < H; h += 1024) {
        float acc = 0.f;
        #pragma unroll
        for (int l = 0; l < ML; ++l)
            acc += s_w[l] * enc_outs[(size_t)l * H + h];
        ws[WS_ATT + h] = acc;
    }
}

// ---------------- Kernel 2: combine GEMV (H x 2H) + bias + relu ----------------
// 1 row/wave, 4 rows/block, direct L2-hot reads of cat, nt weight stream.
__global__ __launch_bounds__(256)
void k2_combine(const float* __restrict__ W_comb, const float* __restrict__ b_comb,
                float* __restrict__ ws)
{
    const int tid = threadIdx.x;
    const int wave = tid >> 6, lane = tid & 63;
    const int k = blockIdx.x * 4 + wave;
    const f4v* w4 = reinterpret_cast<const f4v*>(W_comb + (size_t)k * (2 * H));
    const f4v* c4 = reinterpret_cast<const f4v*>(ws + WS_EMB);
    float acc = 0.f;
    #pragma unroll
    for (int t = 0; t < 16; ++t) {
        int idx = t * 64 + lane;
        acc += dot4(ntload(&w4[idx]), c4[idx]);
    }
    #pragma unroll
    for (int off = 32; off; off >>= 1) acc += __shfl_xor(acc, off);
    if (lane == 0) ws[WS_X + k] = fmaxf(acc + b_comb[k], 0.f);
}

// ---------------- Kernel 3: GRU cell (6 GEMV rows per output element) ----------------
__global__ __launch_bounds__(256)
void k3_gru(const float* __restrict__ W_ih, const float* __restrict__ W_hh,
            const float* __restrict__ b_ih, const float* __restrict__ b_hh,
            const float* __restrict__ hidden, const float* __restrict__ ws,
            float* __restrict__ h_out)
{
    const int tid = threadIdx.x;
    const int wave = tid >> 6, lane = tid & 63;
    const int k = blockIdx.x * 4 + wave;
    const f4v* x4 = reinterpret_cast<const f4v*>(ws + WS_X);
    const f4v* h4 = reinterpret_cast<const f4v*>(hidden);
    const f4v* wi_r = reinterpret_cast<const f4v*>(W_ih + (size_t)k * H);
    const f4v* wi_z = reinterpret_cast<const f4v*>(W_ih + (size_t)(k + H) * H);
    const f4v* wi_n = reinterpret_cast<const f4v*>(W_ih + (size_t)(k + 2 * H) * H);
    const f4v* wh_r = reinterpret_cast<const f4v*>(W_hh + (size_t)k * H);
    const f4v* wh_z = reinterpret_cast<const f4v*>(W_hh + (size_t)(k + H) * H);
    const f4v* wh_n = reinterpret_cast<const f4v*>(W_hh + (size_t)(k + 2 * H) * H);

    float a_r = 0, a_z = 0, a_n = 0, g_r = 0, g_z = 0, g_n = 0;
    #pragma unroll
    for (int t = 0; t < 8; ++t) {
        int idx = t * 64 + lane;
        f4v xv = x4[idx], hv = h4[idx];
        a_r += dot4(ntload(&wi_r[idx]), xv);
        a_z += dot4(ntload(&wi_z[idx]), xv);
        a_n += dot4(ntload(&wi_n[idx]), xv);
        g_r += dot4(ntload(&wh_r[idx]), hv);
        g_z += dot4(ntload(&wh_z[idx]), hv);
        g_n += dot4(ntload(&wh_n[idx]), hv);
    }
    #pragma unroll
    for (int off = 32; off; off >>= 1) {
        a_r += __shfl_xor(a_r, off); a_z += __shfl_xor(a_z, off); a_n += __shfl_xor(a_n, off);
        g_r += __shfl_xor(g_r, off); g_z += __shfl_xor(g_z, off); g_n += __shfl_xor(g_n, off);
    }
    if (lane == 0) {
        float ir = a_r + b_ih[k], iz = a_z + b_ih[k + H], inn = a_n + b_ih[k + 2 * H];
        float hr = g_r + b_hh[k], hz = g_z + b_hh[k + H], hn = g_n + b_hh[k + 2 * H];
        float r = 1.f / (1.f + expf(-(ir + hr)));
        float z = 1.f / (1.f + expf(-(iz + hz)));
        float n = tanhf(inn + r * hn);
        h_out[k] = (1.f - z) * n + z * hidden[k];
    }
}

// ---------------- Kernel 4: vocab projection GEMV (V x H) + block partials ----------------
// 2 rows per wave, 8 rows per block. h preloaded into 32 VGPRs. nt weight stream.
// Emits per-block (max, sumexp) partials for log-softmax.
__global__ __launch_bounds__(256)
void k4_logits(const float* __restrict__ W_out, const float* __restrict__ b_out,
               const float* __restrict__ h_new, float* __restrict__ logits,
               float* __restrict__ ws)
{
    __shared__ float s_val[8];
    const int tid = threadIdx.x;
    if (tid < 8) s_val[tid] = -INFINITY;
    const int wave = tid >> 6, lane = tid & 63;
    const int row0 = blockIdx.x * 8 + wave * 2;
    const int row1 = row0 + 1;
    const bool v0 = row0 < V, v1 = row1 < V;
    const size_t r0 = v0 ? (size_t)row0 : 0;   // clamp: loads stay valid, writes guarded
    const size_t r1 = v1 ? (size_t)row1 : 0;

    const f4v* h4 = reinterpret_cast<const f4v*>(h_new);
    f4v hv[8];
    #pragma unroll
    for (int t = 0; t < 8; ++t) hv[t] = h4[t * 64 + lane];

    const f4v* w0 = reinterpret_cast<const f4v*>(W_out + r0 * H);
    const f4v* w1 = reinterpret_cast<const f4v*>(W_out + r1 * H);
    float a0 = 0.f, a1 = 0.f;
    #pragma unroll
    for (int t = 0; t < 8; ++t) {
        int idx = t * 64 + lane;
        a0 += dot4(ntload(&w0[idx]), hv[t]);
        a1 += dot4(ntload(&w1[idx]), hv[t]);
    }
    #pragma unroll
    for (int off = 32; off; off >>= 1) {
        a0 += __shfl_xor(a0, off);
        a1 += __shfl_xor(a1, off);
    }
    __syncthreads();   // s_val init visible
    if (lane == 0) {
        if (v0) { float l0 = a0 + b_out[row0]; logits[row0] = l0; s_val[wave * 2]     = l0; }
        if (v1) { float l1 = a1 + b_out[row1]; logits[row1] = l1; s_val[wave * 2 + 1] = l1; }
    }
    __syncthreads();
    if (tid == 0) {
        float m = s_val[0];
        #pragma unroll
        for (int i = 1; i < 8; ++i) m = fmaxf(m, s_val[i]);
        float s = 0.f;
        #pragma unroll
        for (int i = 0; i < 8; ++i) s += expf(s_val[i] - m);   // exp(-inf - m) = 0
        ws[WS_PM + blockIdx.x] = m;
        ws[WS_PS + blockIdx.x] = s;
    }
}

// ---------------- Kernel 5: combine per-block partials -> M, log-sum-exp ----------------
__global__ __launch_bounds__(1024)
void k5_combine(float* ws)
{
    __shared__ float s_red[16];
    const int tid = threadIdx.x;
    const int wave = tid >> 6, lane = tid & 63;
    const float* pm = ws + WS_PM;
    const float* ps = ws + WS_PS;

    float m = -INFINITY;
    for (int i = tid; i < NB4; i += 1024) m = fmaxf(m, pm[i]);
    #pragma unroll
    for (int off = 32; off; off >>= 1) m = fmaxf(m, __shfl_xor(m, off));
    if (lane == 0) s_red[wave] = m;
    __syncthreads();
    if (tid == 0) {
        float mm = s_red[0];
        for (int w = 1; w < 16; ++w) mm = fmaxf(mm, s_red[w]);
        s_red[0] = mm;
    }
    __syncthreads();
    m = s_red[0];
    __syncthreads();

    float s = 0.f;
    for (int i = tid; i < NB4; i += 1024) s += ps[i] * expf(pm[i] - m);
    #pragma unroll
    for (int off = 32; off; off >>= 1) s += __shfl_xor(s, off);
    if (lane == 0) s_red[wave] = s;
    __syncthreads();
    if (tid == 0) {
        float ss = 0.f;
        for (int w = 0; w < 16; ++w) ss += s_red[w];
        ws[WS_M] = m;
        ws[WS_L] = logf(ss);
    }
}

// ---------------- Kernel 6: apply log-softmax in place ----------------
__global__ __launch_bounds__(256)
void k6_apply(float* logits, const float* ws)
{
    const int v = blockIdx.x * 256 + threadIdx.x;
    if (v < V) logits[v] = logits[v] - ws[WS_M] - ws[WS_L];
}

extern "C" void kernel_launch(void* const* d_in, const int* in_sizes, int n_in,
                              void* d_out, int out_size, void* d_ws, size_t ws_size,
                              hipStream_t stream)
{
    const int*   tok      = (const int*)d_in[0];     // int64, read low word
    const float* hidden   = (const float*)d_in[1];   // [1,1,H]
    // d_in[2] = encoder_output: unused by reference
    const float* enc_outs = (const float*)d_in[3];   // [ML,H]
    const float* emb      = (const float*)d_in[4];   // [V,H]
    const float* W_attn   = (const float*)d_in[5];   // [ML,2H]
    const float* b_attn   = (const float*)d_in[6];
    const float* W_comb   = (const float*)d_in[7];   // [H,2H]
    const float* b_comb   = (const float*)d_in[8];
    const float* W_ih     = (const float*)d_in[9];   // [3H,H]
    const float* W_hh     = (const float*)d_in[10];  // [3H,H]
    const float* b_ih     = (const float*)d_in[11];
    const float* b_hh     = (const float*)d_in[12];
    const float* W_out    = (const float*)d_in[13];  // [V,H]
    const float* b_out    = (const float*)d_in[14];

    float* out    = (float*)d_out;
    float* ws     = (float*)d_ws;
    float* logits = out;            // [0, V)
    float* h_out  = out + V;        // [V, V+H)
    float* attnw  = out + V + H;    // [V+H, V+H+ML)

    k1_attn   <<<1,            1024, 0, stream>>>(tok, hidden, enc_outs, emb, W_attn, b_attn, ws, attnw);
    k2_combine<<<H / 4,         256, 0, stream>>>(W_comb, b_comb, ws);
    k3_gru    <<<H / 4,         256, 0, stream>>>(W_ih, W_hh, b_ih, b_hh, hidden, ws, h_out);
    k4_logits <<<NB4,           256, 0, stream>>>(W_out, b_out, h_out, logits, ws);
    k5_combine<<<1,            1024, 0, stream>>>(ws);
    k6_apply  <<<(V + 255) / 256, 256, 0, stream>>>(logits, ws);
}